// Round 1
// baseline (83.318 us; speedup 1.0000x reference)
//
#include <hip/hip_runtime.h>

#define BATCH 8
#define NPTS  4096
#define TPB   256

// grid = 2 (directions) * BATCH * (NPTS / TPB) = 256 blocks
// dir 0: for each point of xyz1, min sq-dist over xyz2  -> out[0      .. 32767]
// dir 1: for each point of xyz2, min sq-dist over xyz1  -> out[32768 .. 65535]
__global__ __launch_bounds__(TPB) void nnd_kernel(
    const float* __restrict__ xyz1,
    const float* __restrict__ xyz2,
    float* __restrict__ out)
{
    const int bid  = blockIdx.x;
    const int dir  = bid >> 7;        // 128 blocks per direction
    const int sub  = bid & 127;
    const int b    = sub >> 4;        // NPTS/TPB = 16 tiles per batch
    const int tile = sub & 15;

    const float* q = (dir == 0) ? xyz1 : xyz2;  // query cloud
    const float* r = (dir == 0) ? xyz2 : xyz1;  // reference cloud

    const int n = tile * TPB + (int)threadIdx.x;
    const float* qp = q + ((size_t)b * NPTS + n) * 3;
    const float qx = qp[0], qy = qp[1], qz = qp[2];

    // Stage the whole reference cloud for this batch into LDS (48 KB).
    __shared__ float s[NPTS * 3];
    {
        const float4* rb4 = (const float4*)(r + (size_t)b * NPTS * 3);
        float4*       s4  = (float4*)s;
        // NPTS*3/4 = 3072 float4s, 12 per thread
        #pragma unroll
        for (int i = 0; i < (NPTS * 3 / 4) / TPB; ++i)
            s4[(int)threadIdx.x + i * TPB] = rb4[(int)threadIdx.x + i * TPB];
    }
    __syncthreads();

    // Scan all reference points; broadcast LDS reads (all lanes same addr).
    // Unroll x4 with independent accumulators: 12 contiguous floats per
    // step -> 3 aligned ds_read_b128; min chains stay parallel.
    float best0 = 1e30f, best1 = 1e30f, best2 = 1e30f, best3 = 1e30f;
    for (int m = 0; m < NPTS; m += 4) {
        const float* p = s + m * 3;
        float dx0 = qx - p[0],  dy0 = qy - p[1],  dz0 = qz - p[2];
        float dx1 = qx - p[3],  dy1 = qy - p[4],  dz1 = qz - p[5];
        float dx2 = qx - p[6],  dy2 = qy - p[7],  dz2 = qz - p[8];
        float dx3 = qx - p[9],  dy3 = qy - p[10], dz3 = qz - p[11];
        float d0 = dx0 * dx0 + dy0 * dy0 + dz0 * dz0;
        float d1 = dx1 * dx1 + dy1 * dy1 + dz1 * dz1;
        float d2 = dx2 * dx2 + dy2 * dy2 + dz2 * dz2;
        float d3 = dx3 * dx3 + dy3 * dy3 + dz3 * dz3;
        best0 = fminf(best0, d0);
        best1 = fminf(best1, d1);
        best2 = fminf(best2, d2);
        best3 = fminf(best3, d3);
    }
    float best = fminf(fminf(best0, best1), fminf(best2, best3));

    out[(size_t)dir * (BATCH * NPTS) + (size_t)b * NPTS + n] = best;
}

extern "C" void kernel_launch(void* const* d_in, const int* in_sizes, int n_in,
                              void* d_out, int out_size, void* d_ws, size_t ws_size,
                              hipStream_t stream) {
    const float* xyz1 = (const float*)d_in[0];
    const float* xyz2 = (const float*)d_in[1];
    float* out = (float*)d_out;

    const int grid = 2 * BATCH * (NPTS / TPB);  // 256
    nnd_kernel<<<grid, TPB, 0, stream>>>(xyz1, xyz2, out);
}

// Round 2
// 53.248 us; speedup vs baseline: 1.5647x; 1.5647x over previous
//
#include <hip/hip_runtime.h>

#define BATCH  8
#define NPTS   4096
#define TPB    256
#define NSEG   8
#define SEG    (NPTS / NSEG)     // 512 reference points per segment
#define TILES  (NPTS / TPB)      // 16 query tiles per batch
#define CLOUD  (BATCH * NPTS)    // 32768 points per cloud
#define QTOTAL (2 * CLOUD)       // 65536 outputs

// out[i] = +inf (as int bits) so atomicMin works; runs every call (harness
// poisons once, never re-poisons — we must re-init each launch).
__global__ __launch_bounds__(TPB) void nnd_init(int* out) {
    out[blockIdx.x * TPB + threadIdx.x] = 0x7f800000;  // +inf
}

// Preprocess both clouds: point (x,y,z) -> (-2x, -2y, -2z, x^2+y^2+z^2).
// Layout in ws: [cloud0: 32768 float4][cloud1: 32768 float4].
__global__ __launch_bounds__(TPB) void nnd_prep(const float* __restrict__ xyz1,
                                                const float* __restrict__ xyz2,
                                                float4* __restrict__ pre) {
    int i = blockIdx.x * TPB + (int)threadIdx.x;       // 0..65535
    const float* src = (i < CLOUD) ? xyz1 : xyz2;
    int j = (i < CLOUD) ? i : i - CLOUD;
    float x = src[3 * j + 0];
    float y = src[3 * j + 1];
    float z = src[3 * j + 2];
    pre[i] = make_float4(-2.f * x, -2.f * y, -2.f * z, x * x + y * y + z * z);
}

// Main: each block = (dir, batch, query-tile, ref-segment). Threads own one
// query point, scan SEG preprocessed reference points with block-uniform
// addresses (scalarizes to s_load), combine partial mins via atomicMin.
__global__ __launch_bounds__(TPB, 8) void nnd_main(const float* __restrict__ xyz1,
                                                   const float* __restrict__ xyz2,
                                                   const float4* __restrict__ pre,
                                                   int* __restrict__ out) {
    const int bid  = blockIdx.x;              // 2048 blocks
    const int seg  = bid & (NSEG - 1);        // 3 bits
    const int tile = (bid >> 3) & (TILES - 1);// 4 bits
    const int b    = (bid >> 7) & (BATCH - 1);// 3 bits
    const int dir  = bid >> 10;               // 1 bit

    const float*  q = (dir == 0) ? xyz1 : xyz2;
    const float4* r = pre + (dir == 0 ? 1 : 0) * CLOUD + b * NPTS + seg * SEG;

    const int n = tile * TPB + (int)threadIdx.x;
    const float* qp = q + ((size_t)b * NPTS + n) * 3;
    const float qx = qp[0], qy = qp[1], qz = qp[2];
    const float sqq = qx * qx + qy * qy + qz * qz;

    float best[8];
    #pragma unroll
    for (int i = 0; i < 8; ++i) best[i] = 1e30f;

    for (int m = 0; m < SEG; m += 8) {
        #pragma unroll
        for (int i = 0; i < 8; ++i) {
            float4 p = r[m + i];                 // block-uniform -> s_load
            float e = fmaf(p.x, qx, p.w);        // r2 - 2 q.r  (sqq added later)
            e = fmaf(p.y, qy, e);
            e = fmaf(p.z, qz, e);
            best[i] = fminf(best[i], e);
        }
    }

    float b0 = fminf(fminf(best[0], best[1]), fminf(best[2], best[3]));
    float b1 = fminf(fminf(best[4], best[5]), fminf(best[6], best[7]));
    float bb = sqq + fminf(b0, b1);

    // All candidates are >= 0 up to tiny rounding; int ordering == float
    // ordering for non-negative floats. atomicMin is commutative -> result
    // deterministic across replays.
    atomicMin(out + (dir * CLOUD + b * NPTS + n), __float_as_int(bb));
}

extern "C" void kernel_launch(void* const* d_in, const int* in_sizes, int n_in,
                              void* d_out, int out_size, void* d_ws, size_t ws_size,
                              hipStream_t stream) {
    const float* xyz1 = (const float*)d_in[0];
    const float* xyz2 = (const float*)d_in[1];
    float4* pre = (float4*)d_ws;               // 65536 * 16 B = 1 MB
    int* out = (int*)d_out;

    nnd_init<<<QTOTAL / TPB, TPB, 0, stream>>>(out);
    nnd_prep<<<QTOTAL / TPB, TPB, 0, stream>>>(xyz1, xyz2, pre);
    nnd_main<<<2 * BATCH * TILES * NSEG, TPB, 0, stream>>>(xyz1, xyz2, pre, out);
}

// Round 3
// 36.772 us; speedup vs baseline: 2.2658x; 1.4480x over previous
//
#include <hip/hip_runtime.h>

#define BATCH  8
#define NPTS   4096
#define TPB    256
#define QPT    4                    // queries per thread
#define QPB    (TPB * QPT)          // 1024 queries per block
#define QTILES (NPTS / QPB)         // 4 query tiles per batch
#define NSEG   32
#define SEG    (NPTS / NSEG)        // 128 ref points per block
#define NPAIRS (NPTS / 2)           // 2048 ref pairs per batch cloud
#define HCLOUD (BATCH * NPAIRS)     // 16384 pairs per cloud
#define CLOUD  (BATCH * NPTS)       // 32768 points per cloud

typedef float v2f __attribute__((ext_vector_type(2)));

// One thread per ref PAIR (32768 total): writes pair-transposed preprocessed
// layout   pre[2p]   = (-2x0, -2x1, -2y0, -2y1)
//          pre[2p+1] = (-2z0, -2z1,  w0,   w1)   w = x^2+y^2+z^2
// and also re-inits both output halves to +inf for the atomicMin pass
// (harness poisons once; we must re-init every launch).
__global__ __launch_bounds__(TPB) void nnd_prep(const float* __restrict__ xyz1,
                                                const float* __restrict__ xyz2,
                                                float4* __restrict__ pre,
                                                int* __restrict__ out) {
    int i = blockIdx.x * TPB + (int)threadIdx.x;       // 0..32767 (pair id)
    out[i]         = 0x7f800000;                       // +inf
    out[i + CLOUD] = 0x7f800000;

    const float* src = (i < HCLOUD) ? xyz1 : xyz2;
    int j = (i < HCLOUD) ? i : i - HCLOUD;             // pair within cloud
    const float* p = src + (size_t)j * 6;
    float x0 = p[0], y0 = p[1], z0 = p[2];
    float x1 = p[3], y1 = p[4], z1 = p[5];
    float w0 = x0 * x0 + y0 * y0 + z0 * z0;
    float w1 = x1 * x1 + y1 * y1 + z1 * z1;
    pre[2 * i + 0] = make_float4(-2.f * x0, -2.f * x1, -2.f * y0, -2.f * y1);
    pre[2 * i + 1] = make_float4(-2.f * z0, -2.f * z1, w0, w1);
}

// Main: block = (dir, batch, qtile, segment). Each thread owns QPT=4
// consecutive query points (3 coalesced float4 loads), scans SEG/2 ref pairs
// via block-uniform s_loads, packed-fp32 fma chains + min3 reduction.
__global__ __launch_bounds__(TPB, 8) void nnd_main(const float* __restrict__ xyz1,
                                                   const float* __restrict__ xyz2,
                                                   const float4* __restrict__ pre,
                                                   int* __restrict__ out) {
    const int bid  = blockIdx.x;                 // 2048 blocks
    const int seg  = bid & (NSEG - 1);           // 5 bits
    const int tile = (bid >> 5) & (QTILES - 1);  // 2 bits
    const int b    = (bid >> 7) & (BATCH - 1);   // 3 bits
    const int dir  = bid >> 10;                  // 1 bit

    const float*  q  = (dir == 0) ? xyz1 : xyz2;
    const float4* rp = pre + 2 * ((size_t)(dir == 0 ? 1 : 0) * HCLOUD
                                  + (size_t)b * NPAIRS + (size_t)seg * (SEG / 2));

    // 4 consecutive queries per thread: 12 floats = 3 aligned float4 loads.
    const int n0 = tile * QPB + (int)threadIdx.x * QPT;
    const float4* qv = (const float4*)(q + ((size_t)b * NPTS + n0) * 3);
    float4 qa = qv[0], qb = qv[1], qc = qv[2];
    float qx[QPT] = {qa.x, qa.w, qb.z, qc.y};
    float qy[QPT] = {qa.y, qb.x, qb.w, qc.z};
    float qz[QPT] = {qa.z, qb.y, qc.x, qc.w};

    v2f qx2[QPT], qy2[QPT], qz2[QPT];
    #pragma unroll
    for (int k = 0; k < QPT; ++k) {
        qx2[k] = (v2f){qx[k], qx[k]};
        qy2[k] = (v2f){qy[k], qy[k]};
        qz2[k] = (v2f){qz[k], qz[k]};
    }

    float best[QPT];
    #pragma unroll
    for (int k = 0; k < QPT; ++k) best[k] = 1e30f;

    #pragma unroll 4
    for (int p = 0; p < SEG / 2; ++p) {
        float4 A = rp[2 * p];        // block-uniform -> s_load
        float4 Bv = rp[2 * p + 1];
        v2f x01 = (v2f){A.x, A.y};
        v2f y01 = (v2f){A.z, A.w};
        v2f z01 = (v2f){Bv.x, Bv.y};
        v2f w01 = (v2f){Bv.z, Bv.w};
        #pragma unroll
        for (int k = 0; k < QPT; ++k) {
            v2f e = x01 * qx2[k] + w01;   // v_pk_fma_f32 (contract)
            e = y01 * qy2[k] + e;
            e = z01 * qz2[k] + e;
            best[k] = fminf(best[k], fminf(e.x, e.y));  // v_min3_f32
        }
    }

    // Add per-query ||q||^2 at the end; combine partials across segments via
    // int atomicMin (valid: all candidates non-negative; commutative ->
    // deterministic across graph replays).
    int* o = out + (size_t)dir * CLOUD + (size_t)b * NPTS + n0;
    #pragma unroll
    for (int k = 0; k < QPT; ++k) {
        float sqq = qx[k] * qx[k] + qy[k] * qy[k] + qz[k] * qz[k];
        atomicMin(o + k, __float_as_int(best[k] + sqq));
    }
}

extern "C" void kernel_launch(void* const* d_in, const int* in_sizes, int n_in,
                              void* d_out, int out_size, void* d_ws, size_t ws_size,
                              hipStream_t stream) {
    const float* xyz1 = (const float*)d_in[0];
    const float* xyz2 = (const float*)d_in[1];
    float4* pre = (float4*)d_ws;               // 32768 pairs * 32 B = 1 MB
    int* out = (int*)d_out;

    nnd_prep<<<(2 * HCLOUD) / TPB, TPB, 0, stream>>>(xyz1, xyz2, pre, out);
    nnd_main<<<2 * BATCH * QTILES * NSEG, TPB, 0, stream>>>(xyz1, xyz2, pre, out);
}

// Round 4
// 36.424 us; speedup vs baseline: 2.2875x; 1.0096x over previous
//
#include <hip/hip_runtime.h>

#define BATCH  8
#define NPTS   4096
#define TPB    256
#define QPT    2                    // queries per thread
#define QPB    (TPB * QPT)          // 512 queries per block
#define QTILES (NPTS / QPB)         // 8 query tiles per batch
#define NSEG   16
#define SEG    (NPTS / NSEG)        // 256 ref points per block
#define NPAIRS (NPTS / 2)           // 2048 ref pairs per batch cloud
#define HCLOUD (BATCH * NPAIRS)     // 16384 pairs per cloud
#define CLOUD  (BATCH * NPTS)       // 32768 points per cloud
#define QTOTAL (2 * CLOUD)          // 65536 outputs

typedef float v2f __attribute__((ext_vector_type(2)));

// ws layout: [pre: 32768 pairs * 32 B = 1 MB][partials: 16 dirb * 16 seg * 4096 * 4 B = 4 MB]
#define PART_OFF (2 * HCLOUD * 2)   // in float4 units: 65536 float4 = 1 MB

// One thread per ref PAIR (32768 total): pair-transposed preprocessed layout
//   pre[2p]   = (-2x0, -2x1, -2y0, -2y1)
//   pre[2p+1] = (-2z0, -2z1,  w0,   w1)   w = x^2+y^2+z^2
__global__ __launch_bounds__(TPB) void nnd_prep(const float* __restrict__ xyz1,
                                                const float* __restrict__ xyz2,
                                                float4* __restrict__ pre) {
    int i = blockIdx.x * TPB + (int)threadIdx.x;       // 0..32767 (pair id)
    const float* src = (i < HCLOUD) ? xyz1 : xyz2;
    int j = (i < HCLOUD) ? i : i - HCLOUD;             // pair within cloud
    const float* p = src + (size_t)j * 6;
    float x0 = p[0], y0 = p[1], z0 = p[2];
    float x1 = p[3], y1 = p[4], z1 = p[5];
    float w0 = x0 * x0 + y0 * y0 + z0 * z0;
    float w1 = x1 * x1 + y1 * y1 + z1 * z1;
    pre[2 * i + 0] = make_float4(-2.f * x0, -2.f * x1, -2.f * y0, -2.f * y1);
    pre[2 * i + 1] = make_float4(-2.f * z0, -2.f * z1, w0, w1);
}

// Main: block = (dir, batch, qtile, segment). Thread owns QPT=2 consecutive
// query points, scans SEG/2 ref pairs via block-uniform s_loads, packed-fp32
// fma chains + min3. Stores one partial per query to ws (plain store — NO
// atomics; a reduce kernel folds segments).
__global__ __launch_bounds__(TPB, 8) void nnd_main(const float* __restrict__ xyz1,
                                                   const float* __restrict__ xyz2,
                                                   const float4* __restrict__ pre,
                                                   float* __restrict__ part) {
    const int bid  = blockIdx.x;                 // 2048 blocks
    const int seg  = bid & (NSEG - 1);           // 4 bits
    const int tile = (bid >> 4) & (QTILES - 1);  // 3 bits
    const int b    = (bid >> 7) & (BATCH - 1);   // 3 bits
    const int dir  = bid >> 10;                  // 1 bit

    const float*  q  = (dir == 0) ? xyz1 : xyz2;
    const float4* rp = pre + 2 * ((size_t)(dir == 0 ? 1 : 0) * HCLOUD
                                  + (size_t)b * NPAIRS + (size_t)seg * (SEG / 2));

    // 2 consecutive queries per thread: 6 floats = 3 aligned float2 loads.
    const int n0 = tile * QPB + (int)threadIdx.x * QPT;
    const float2* qv = (const float2*)(q + ((size_t)b * NPTS + n0) * 3);
    float2 f0 = qv[0], f1 = qv[1], f2 = qv[2];
    const float qx[QPT] = {f0.x, f1.y};
    const float qy[QPT] = {f0.y, f2.x};
    const float qz[QPT] = {f1.x, f2.y};

    v2f qx2[QPT], qy2[QPT], qz2[QPT];
    #pragma unroll
    for (int k = 0; k < QPT; ++k) {
        qx2[k] = (v2f){qx[k], qx[k]};
        qy2[k] = (v2f){qy[k], qy[k]};
        qz2[k] = (v2f){qz[k], qz[k]};
    }

    float best[QPT];
    #pragma unroll
    for (int k = 0; k < QPT; ++k) best[k] = 1e30f;

    #pragma unroll 4
    for (int p = 0; p < SEG / 2; ++p) {
        float4 A  = rp[2 * p];          // block-uniform -> s_load (32 B/iter)
        float4 Bv = rp[2 * p + 1];
        v2f x01 = (v2f){A.x, A.y};
        v2f y01 = (v2f){A.z, A.w};
        v2f z01 = (v2f){Bv.x, Bv.y};
        v2f w01 = (v2f){Bv.z, Bv.w};    // one SGPR->VGPR materialization/iter
        #pragma unroll
        for (int k = 0; k < QPT; ++k) {
            v2f e = x01 * qx2[k] + w01;   // v_pk_fma_f32
            e = y01 * qy2[k] + e;
            e = z01 * qz2[k] + e;
            best[k] = fminf(best[k], fminf(e.x, e.y));  // v_min3_f32
        }
    }

    // part[(dir*BATCH+b)][seg][n] — coalesced float2 store per thread.
    float* dst = part + ((size_t)(dir * BATCH + b) * NSEG + seg) * NPTS + n0;
    float2 r;
    r.x = best[0] + (qx[0] * qx[0] + qy[0] * qy[0] + qz[0] * qz[0]);
    r.y = best[1] + (qx[1] * qx[1] + qy[1] * qy[1] + qz[1] * qz[1]);
    *(float2*)dst = r;
}

// Fold the NSEG partials per query. part[(dir*BATCH+b)][seg][n] -> out.
__global__ __launch_bounds__(TPB) void nnd_reduce(const float* __restrict__ part,
                                                  float* __restrict__ out) {
    int qid = blockIdx.x * TPB + (int)threadIdx.x;    // 0..65535
    int db = qid >> 12;                               // dir*BATCH+b
    int n  = qid & (NPTS - 1);
    const float* p = part + (size_t)db * NSEG * NPTS + n;
    float m = p[0];
    #pragma unroll
    for (int s = 1; s < NSEG; ++s) m = fminf(m, p[(size_t)s * NPTS]);
    out[qid] = m;
}

extern "C" void kernel_launch(void* const* d_in, const int* in_sizes, int n_in,
                              void* d_out, int out_size, void* d_ws, size_t ws_size,
                              hipStream_t stream) {
    const float* xyz1 = (const float*)d_in[0];
    const float* xyz2 = (const float*)d_in[1];
    float4* pre  = (float4*)d_ws;
    float*  part = (float*)d_ws + 4 * (size_t)PART_OFF;  // after 1 MB of pre
    float*  out  = (float*)d_out;

    nnd_prep<<<(2 * HCLOUD) / TPB, TPB, 0, stream>>>(xyz1, xyz2, pre);
    nnd_main<<<2 * BATCH * QTILES * NSEG, TPB, 0, stream>>>(xyz1, xyz2, pre, part);
    nnd_reduce<<<QTOTAL / TPB, TPB, 0, stream>>>(part, out);
}

// Round 5
// 34.529 us; speedup vs baseline: 2.4130x; 1.0549x over previous
//
#include <hip/hip_runtime.h>

#define BATCH  8
#define NPTS   4096
#define TPB    256
#define QPT    2                    // queries per thread
#define QPB    (TPB * QPT)          // 512 queries per block
#define QTILES (NPTS / QPB)         // 8 query tiles per batch
#define NSEG   16
#define SEG    (NPTS / NSEG)        // 256 ref points per block
#define SPAIR  (SEG / 2)            // 128 ref pairs per block
#define NPAIRS (NPTS / 2)           // 2048 ref pairs per batch cloud
#define HCLOUD (BATCH * NPAIRS)     // 16384 pairs per cloud
#define CLOUD  (BATCH * NPTS)       // 32768 points per cloud
#define QTOTAL (2 * CLOUD)          // 65536 outputs

typedef float v2f __attribute__((ext_vector_type(2)));
typedef float v4f __attribute__((ext_vector_type(4)));

// Guaranteed packed fp32 fma (2 lanes/inst). All-VGPR operands by design.
__device__ inline v2f pk_fma(v2f a, v2f b, v2f c) {
    v2f d;
    asm("v_pk_fma_f32 %0, %1, %2, %3" : "=v"(d) : "v"(a), "v"(b), "v"(c));
    return d;
}
__device__ inline float fmin3(float a, float b, float c) {
    float d;
    asm("v_min3_f32 %0, %1, %2, %3" : "=v"(d) : "v"(a), "v"(b), "v"(c));
    return d;
}

// ws layout: [pre: 32768 pairs * 32 B = 1 MB][part: 16 dirb * 16 seg * 4096 * 4 B = 4 MB]
#define PART_OFF_FLOATS (2 * HCLOUD * 2 * 4)

// One thread per ref PAIR: pair-transposed preprocessed layout
//   pre[2p]   = (-2x0, -2x1, -2y0, -2y1)
//   pre[2p+1] = (-2z0, -2z1,  w0,   w1)   w = x^2+y^2+z^2
__global__ __launch_bounds__(TPB) void nnd_prep(const float* __restrict__ xyz1,
                                                const float* __restrict__ xyz2,
                                                v4f* __restrict__ pre) {
    int i = blockIdx.x * TPB + (int)threadIdx.x;       // 0..32767 (pair id)
    const float* src = (i < HCLOUD) ? xyz1 : xyz2;
    int j = (i < HCLOUD) ? i : i - HCLOUD;
    const float* p = src + (size_t)j * 6;
    float x0 = p[0], y0 = p[1], z0 = p[2];
    float x1 = p[3], y1 = p[4], z1 = p[5];
    float w0 = x0 * x0 + y0 * y0 + z0 * z0;
    float w1 = x1 * x1 + y1 * y1 + z1 * z1;
    pre[2 * i + 0] = (v4f){-2.f * x0, -2.f * x1, -2.f * y0, -2.f * y1};
    pre[2 * i + 1] = (v4f){-2.f * z0, -2.f * z1, w0, w1};
}

// Main: block = (dir, batch, qtile, segment). Stage the segment's
// preprocessed pairs into LDS (4 KB); uniform-address ds_read_b128
// broadcasts put ref operands in VGPRs -> pure-VGPR pk_fma chains.
__global__ __launch_bounds__(TPB, 8) void nnd_main(const float* __restrict__ xyz1,
                                                   const float* __restrict__ xyz2,
                                                   const v4f* __restrict__ pre,
                                                   float* __restrict__ part) {
    const int bid  = blockIdx.x;                 // 2048 blocks
    const int seg  = bid & (NSEG - 1);           // 4 bits
    const int tile = (bid >> 4) & (QTILES - 1);  // 3 bits
    const int b    = (bid >> 7) & (BATCH - 1);   // 3 bits
    const int dir  = bid >> 10;                  // 1 bit

    __shared__ v4f s[2 * SPAIR];                 // 256 x 16 B = 4 KB

    // Stage: 256 float4 = exactly one per thread, coalesced.
    const size_t pairStart = (size_t)(dir == 0 ? 1 : 0) * HCLOUD
                           + (size_t)b * NPAIRS + (size_t)seg * SPAIR;
    s[threadIdx.x] = pre[2 * pairStart + threadIdx.x];

    // Queries: 2 consecutive points per thread (6 floats, aligned float2s).
    const float* q = (dir == 0) ? xyz1 : xyz2;
    const int n0 = tile * QPB + (int)threadIdx.x * QPT;
    const float2* qv = (const float2*)(q + ((size_t)b * NPTS + n0) * 3);
    float2 f0 = qv[0], f1 = qv[1], f2 = qv[2];
    const float qx[QPT] = {f0.x, f1.y};
    const float qy[QPT] = {f0.y, f2.x};
    const float qz[QPT] = {f1.x, f2.y};

    v2f qx2[QPT], qy2[QPT], qz2[QPT];
    #pragma unroll
    for (int k = 0; k < QPT; ++k) {
        qx2[k] = (v2f){qx[k], qx[k]};
        qy2[k] = (v2f){qy[k], qy[k]};
        qz2[k] = (v2f){qz[k], qz[k]};
    }

    float best[QPT] = {1e30f, 1e30f};

    __syncthreads();

    #pragma unroll 8
    for (int p = 0; p < SPAIR; ++p) {
        v4f A = s[2 * p];                        // uniform addr -> broadcast
        v4f B = s[2 * p + 1];
        v2f x01 = __builtin_shufflevector(A, A, 0, 1);
        v2f y01 = __builtin_shufflevector(A, A, 2, 3);
        v2f z01 = __builtin_shufflevector(B, B, 0, 1);
        v2f w01 = __builtin_shufflevector(B, B, 2, 3);
        #pragma unroll
        for (int k = 0; k < QPT; ++k) {
            v2f e = pk_fma(x01, qx2[k], w01);
            e = pk_fma(y01, qy2[k], e);
            e = pk_fma(z01, qz2[k], e);
            best[k] = fmin3(best[k], e.x, e.y);
        }
    }

    // part[(dir*BATCH+b)][seg][n] — coalesced float2 store.
    float* dst = part + ((size_t)(dir * BATCH + b) * NSEG + seg) * NPTS + n0;
    float2 r;
    r.x = best[0] + (qx[0] * qx[0] + qy[0] * qy[0] + qz[0] * qz[0]);
    r.y = best[1] + (qx[1] * qx[1] + qy[1] * qy[1] + qz[1] * qz[1]);
    *(float2*)dst = r;
}

// Fold the NSEG partials per query.
__global__ __launch_bounds__(TPB) void nnd_reduce(const float* __restrict__ part,
                                                  float* __restrict__ out) {
    int qid = blockIdx.x * TPB + (int)threadIdx.x;    // 0..65535
    int db = qid >> 12;                               // dir*BATCH+b
    int n  = qid & (NPTS - 1);
    const float* p = part + (size_t)db * NSEG * NPTS + n;
    float m = p[0];
    #pragma unroll
    for (int sgm = 1; sgm < NSEG; ++sgm) m = fminf(m, p[(size_t)sgm * NPTS]);
    out[qid] = m;
}

extern "C" void kernel_launch(void* const* d_in, const int* in_sizes, int n_in,
                              void* d_out, int out_size, void* d_ws, size_t ws_size,
                              hipStream_t stream) {
    const float* xyz1 = (const float*)d_in[0];
    const float* xyz2 = (const float*)d_in[1];
    v4f*   pre  = (v4f*)d_ws;
    float* part = (float*)d_ws + PART_OFF_FLOATS;
    float* out  = (float*)d_out;

    nnd_prep<<<(2 * HCLOUD) / TPB, TPB, 0, stream>>>(xyz1, xyz2, pre);
    nnd_main<<<2 * BATCH * QTILES * NSEG, TPB, 0, stream>>>(xyz1, xyz2, pre, part);
    nnd_reduce<<<QTOTAL / TPB, TPB, 0, stream>>>(part, out);
}